// Round 8
// baseline (2046.050 us; speedup 1.0000x reference)
//
#include <hip/hip_runtime.h>

// Decoder GRU, B=128 T=512 X=64 H=256, skip=4 (runtime).
// Round 8 = Round 7 with the fast-path skip-tap fixed: skip_p(i) lives at
// ring[i - 2*skip] (skip-list position i-skip maps to buf[pos - skip]), the
// R7 fast path used ring[i - skip] in two places -> absmax 0.498.  Fast path
// now also guarded to 1 <= skip <= 7 (else all-slow-path, which handles the
// general tables()).
//  - 128 WGs x 1024 thr (16 waves, 4/SIMD), 1 batch/WG, zero inter-WG comm.
//  - W_hh fp16 in VGPRs: 24 uint4 = 96 regs/thread (384 KB = 75% of CU RF).
//  - W_ih fp16 in LDS (96 KB); W_out fp16 global (L1-hot, off heavy path).
//  - Steady state: 2 barriers/step (gates on all waves + projection of
//    out(i) on waves 8-15 in phase A; finalize in phase B).
typedef _Float16 h2_t __attribute__((ext_vector_type(2)));

constexpr int T_ = 512;
constexpr int X_ = 64;
constexpr int H_ = 256;
constexpr int NWG = 128;
constexpr int NT = 1024;
constexpr int RS = 16;  // ring slots; fast path needs 2*skip <= 15

constexpr int GHH_U4 = 3 * 4 * 8 * 256;  // 24576 u4 = 384 KB [g][kq][j][c]
constexpr int GIH_U4 = 3 * 4 * 2 * 256;  //  6144 u4 =  96 KB [g][kq][j][c]
constexpr int GOUT_U2 = 64 * 64;         //  4096 u2 =  32 KB [kp2][xc]

__device__ __forceinline__ float sigmoid_f(float x) {
  float e = __expf(fminf(-x, 80.f));
  return 1.f / (1.f + e);
}
__device__ __forceinline__ float tanh_f(float x) {
  float e = __expf(fminf(-2.f * x, 80.f));
  return (1.f - e) / (1.f + e);
}
__device__ __forceinline__ unsigned pk2(float a, float b) {
  h2_t v;
  v[0] = (_Float16)a;
  v[1] = (_Float16)b;
  return __builtin_bit_cast(unsigned, v);
}
__device__ __forceinline__ uint2 pk4(const float* s) {
  return make_uint2(pk2(s[0], s[1]), pk2(s[2], s[3]));
}
__device__ __forceinline__ uint4 pk8(const float* s) {
  return make_uint4(pk2(s[0], s[1]), pk2(s[2], s[3]), pk2(s[4], s[5]),
                    pk2(s[6], s[7]));
}
__device__ __forceinline__ float dotp(unsigned w, unsigned h, float acc) {
  h2_t wv = __builtin_bit_cast(h2_t, w);
  h2_t hv = __builtin_bit_cast(h2_t, h);
#if __has_builtin(__builtin_amdgcn_fdot2)
  return __builtin_amdgcn_fdot2(wv, hv, acc, false);
#else
  acc = fmaf((float)wv[0], (float)hv[0], acc);
  return fmaf((float)wv[1], (float)hv[1], acc);
#endif
}
__device__ __forceinline__ float dotq(uint4 w, uint4 h, float acc) {
  acc = dotp(w.x, h.x, acc);
  acc = dotp(w.y, h.y, acc);
  acc = dotp(w.z, h.z, acc);
  return dotp(w.w, h.w, acc);
}

// One-time fp32 -> fp16 pack + transpose.
__global__ void prep_kernel(const float* __restrict__ Wih,
                            const float* __restrict__ Whh,
                            const float* __restrict__ Wout,
                            uint4* __restrict__ G) {
  int id = blockIdx.x * 256 + threadIdx.x;
  if (id < GHH_U4) {
    int c = id & 255, r = id >> 8;             // r = g*32 + kq*8 + j
    int j = r & 7, kq = (r >> 3) & 3, g = r >> 5;
    G[id] = pk8(Whh + (size_t)(g * 256 + c) * H_ + kq * 64 + j * 8);
  } else if (id < GHH_U4 + GIH_U4) {
    int jd = id - GHH_U4;
    int c = jd & 255, r = jd >> 8;             // r = g*8 + kq*2 + j
    int j = r & 1, kq = (r >> 1) & 3, g = r >> 3;
    G[id] = pk8(Wih + (size_t)(g * 256 + c) * X_ + kq * 16 + j * 8);
  } else if (id < GHH_U4 + GIH_U4 + GOUT_U2 / 2) {
    uint2* Go = (uint2*)(G + GHH_U4 + GIH_U4);
    int jd = (id - GHH_U4 - GIH_U4) * 2;
#pragma unroll
    for (int s = 0; s < 2; ++s) {
      int xc = (jd + s) & 63, kp2 = (jd + s) >> 6;
      Go[jd + s] = pk4(Wout + (size_t)xc * H_ + kp2 * 4);
    }
  }
}

struct Tab {
  float m0, m1;
  bool gz, pz;
  int gi, pi;
};
__device__ __forceinline__ Tab tables(int i, int skip,
                                      const int* __restrict__ mask0,
                                      const int* __restrict__ mask1) {
  Tab tb;
  tb.m0 = (float)mask0[i];
  tb.m1 = (float)mask1[i];
  int pg = (i < skip) ? 2 * i : i - skip;
  tb.gz = pg < skip;
  int gi = pg - skip;
  if (gi < 0) gi = 0;
  if (gi >= i) tb.gz = true;  // unwritten slot == reference's zero init
  tb.gi = gi;
  int pp_ = (i < skip) ? 2 * i + 1 : i - skip;
  tb.pz = pp_ < skip;
  int pi = pp_ - skip;
  if (pi < 0) pi = 0;
  tb.pi = pi;
  return tb;
}

__global__ __launch_bounds__(NT) void decoder_kernel(
    const float* __restrict__ h_enc, const float* __restrict__ b_ih,
    const float* __restrict__ b_hh, const float* __restrict__ b_out,
    const int* __restrict__ mask0, const int* __restrict__ mask1,
    const int* __restrict__ skipp, const uint4* __restrict__ G,
    const uint2* __restrict__ Gout, float* __restrict__ out) {
  __shared__ uint4 wih_l[GIH_U4];                 // 96 KB W_ih fp16
  __shared__ float ring[RS][H_];                  // 16 KB h history
  __shared__ float part[4][4][H_];                // 16 KB gate partials
  __shared__ float pp[8][X_];                     //  2 KB proj partials
  __shared__ alignas(16) unsigned hid2[H_ / 2];   // hidden fp16 pairs
  __shared__ alignas(16) unsigned pt2[H_ / 2];    // proj input fp16 pairs
  __shared__ alignas(16) unsigned xt2[X_ / 2];    // x feedback fp16 pairs

  const int t = threadIdx.x;
  const int b = blockIdx.x;
  const int c = t & 255, kq = t >> 8;
  const int skip = skipp[0];
  // Fast path valid only for 1 <= skip <= 7 (ring lookback 2*skip <= 15 and
  // no zero/unwritten taps after i >= 2*skip).  Otherwise: all slow path.
  const int fs = (skip >= 1 && skip <= 7) ? min(2 * skip, T_) : T_;

  // ---- persistent W_hh registers: 24 uint4 = 96 VGPRs ----
  uint4 whh[24];
#pragma unroll
  for (int g = 0; g < 3; ++g)
#pragma unroll
    for (int j = 0; j < 8; ++j)
      whh[g * 8 + j] = G[(size_t)(g * 32 + kq * 8 + j) * 256 + c];
  // ---- W_ih -> LDS ----
#pragma unroll
  for (int m = 0; m < GIH_U4 / NT; ++m) wih_l[t + NT * m] = G[GHH_U4 + t + NT * m];

  float bsr = 0, bsz = 0, bin_ = 0, bhn_ = 0, hps_reg = 0, hn_reg = 0;
  if (t < H_) {
    bsr = b_ih[t] + b_hh[t];
    bsz = b_ih[H_ + t] + b_hh[H_ + t];
    bin_ = b_ih[2 * H_ + t];
    bhn_ = b_hh[2 * H_ + t];
    float hp = h_enc[(size_t)b * H_ + t];
    hps_reg = hp;
    float h0 = (float)mask0[0] * hp;  // skip_g at i=0 is zero
    float ho = __shfl_xor(h0, 1);
    if (!(t & 1)) hid2[t >> 1] = pk2(h0, ho);
  }
  float bo = 0;
  if (t >= 512 && t < 512 + X_) bo = b_out[t - 512];
  if (t < X_ / 2) xt2[t] = 0u;
  if (t < H_ / 2) pt2[t] = 0u;
  __syncthreads();

  for (int i = 0; i < T_; ++i) {
    const bool fast = (i >= fs);
    float m0n = 0.f, m1n = 0.f;
    if (t < H_ && i + 1 < T_) {
      m0n = (float)mask0[i + 1];
      m1n = (float)mask1[i + 1];
    }

    // ================= phase A =================
    float ar = 0, az = 0, ani = 0, anh = 0;
    {
      const uint4* h4 = (const uint4*)hid2;
#pragma unroll
      for (int j = 0; j < 8; ++j) {
        uint4 h8 = h4[kq * 8 + j];  // wave-uniform broadcast
        ar = dotq(whh[j], h8, ar);
        az = dotq(whh[8 + j], h8, az);
        anh = dotq(whh[16 + j], h8, anh);
      }
      const uint4* x4 = (const uint4*)xt2;
#pragma unroll
      for (int j = 0; j < 2; ++j) {
        uint4 xv = x4[kq * 2 + j];  // broadcast
        ar = dotq(wih_l[(size_t)(0 + kq * 2 + j) * 256 + c], xv, ar);
        az = dotq(wih_l[(size_t)(8 + kq * 2 + j) * 256 + c], xv, az);
        ani = dotq(wih_l[(size_t)(16 + kq * 2 + j) * 256 + c], xv, ani);
      }
    }
    part[kq][0][c] = ar;
    part[kq][1][c] = az;
    part[kq][2][c] = ani;
    part[kq][3][c] = anh;
    if (fast && t >= 512) {  // projection partials for out(i) from pt2(i)
      int xc = t & 63, k8 = (t >> 6) & 7;
      const uint4* p4 = (const uint4*)pt2;
      uint4 pa = p4[k8 * 4], pb = p4[k8 * 4 + 1], pc = p4[k8 * 4 + 2],
            pd = p4[k8 * 4 + 3];
      const uint2* wo = Gout + (size_t)(k8 * 8) * 64 + xc;
      float acc = 0.f;
      uint2 w0 = wo[0], w1 = wo[64], w2 = wo[128], w3 = wo[192];
      uint2 w4 = wo[256], w5 = wo[320], w6 = wo[384], w7 = wo[448];
      acc = dotp(w0.x, pa.x, acc); acc = dotp(w0.y, pa.y, acc);
      acc = dotp(w1.x, pa.z, acc); acc = dotp(w1.y, pa.w, acc);
      acc = dotp(w2.x, pb.x, acc); acc = dotp(w2.y, pb.y, acc);
      acc = dotp(w3.x, pb.z, acc); acc = dotp(w3.y, pb.w, acc);
      acc = dotp(w4.x, pc.x, acc); acc = dotp(w4.y, pc.y, acc);
      acc = dotp(w5.x, pc.z, acc); acc = dotp(w5.y, pc.w, acc);
      acc = dotp(w6.x, pd.x, acc); acc = dotp(w6.y, pd.y, acc);
      acc = dotp(w7.x, pd.z, acc); acc = dotp(w7.y, pd.w, acc);
      pp[k8][xc] = acc;
    }
    __syncthreads();

    // ================= phase B =================
    if (t < H_) {
      float sr = bsr, sz = bsz, sni = bin_, snh = bhn_;
#pragma unroll
      for (int q = 0; q < 4; ++q) {
        sr += part[q][0][t];
        sz += part[q][1][t];
        sni += part[q][2][t];
        snh += part[q][3][t];
      }
      float r = sigmoid_f(sr);
      float z = sigmoid_f(sz);
      float n = tanh_f(sni + r * snh);
      float hv;
      {
        Tab tb = tables(i, skip, mask0, mask1);
        float sg = tb.gz ? 0.f : ring[tb.gi & (RS - 1)][t];
        hv = tb.m0 * hps_reg + tb.m1 * sg;
      }
      float hn = fmaf(z, hv - n, n);  // (1-z)*n + z*hidden
      hn_reg = hn;
      ring[i & (RS - 1)][t] = hn;
      if (fast) {
        if (i + 1 < T_) {
          // skip_p(i+1) = buf[(i+1-skip) - skip] = h(i+1-2*skip)   [BUGFIX]
          float ptn = hn + ring[(i + 1 - 2 * skip) & (RS - 1)][t];
          float hdn = m0n * hn + m1n * ring[(i + 1 - 2 * skip) & (RS - 1)][t] *
                                     0.f;  // placeholder, real below
          // skip_g(i+1) = buf[(i+1-skip) - skip] as well -> same tap
          hdn = m0n * hn + m1n * ring[(i + 1 - 2 * skip) & (RS - 1)][t];
          float po = __shfl_xor(ptn, 1);
          float ho = __shfl_xor(hdn, 1);
          if (!(t & 1)) {
            pt2[t >> 1] = pk2(ptn, po);
            hid2[t >> 1] = pk2(hdn, ho);
          }
        }
      } else {
        Tab tb = tables(i, skip, mask0, mask1);
        float sp = tb.pz ? 0.f : ((tb.pi == i) ? hn : ring[tb.pi & (RS - 1)][t]);
        float ptc = hps_reg + sp;
        float po = __shfl_xor(ptc, 1);
        if (!(t & 1)) pt2[t >> 1] = pk2(ptc, po);
        if (i + 1 < T_) {
          Tab tn = tables(i + 1, skip, mask0, mask1);
          float sg = tn.gz ? 0.f : ring[tn.gi & (RS - 1)][t];
          float hdn = tn.m0 * hn + tn.m1 * sg;
          float ho = __shfl_xor(hdn, 1);
          if (!(t & 1)) hid2[t >> 1] = pk2(hdn, ho);
        }
      }
      hps_reg = hn;
    }
    if (fast && t >= 512 && t < 512 + X_) {  // finalize out(i) + x feedback
      int xc = t - 512;
      float o = bo;
#pragma unroll
      for (int j = 0; j < 8; ++j) o += pp[j][xc];
      out[(size_t)b * T_ * X_ + (size_t)i * X_ + xc] = o;
      float oo = __shfl_xor(o, 1);
      if (!(t & 1)) xt2[xc >> 1] = pk2(o, oo);
    }
    __syncthreads();

    if (!fast) {
      // ---- slow phase C: projection partials from pt2(i) ----
      if (t >= 512) {
        int xc = t & 63, k8 = (t >> 6) & 7;
        const uint4* p4 = (const uint4*)pt2;
        uint4 pa = p4[k8 * 4], pb = p4[k8 * 4 + 1], pc = p4[k8 * 4 + 2],
              pd = p4[k8 * 4 + 3];
        const uint2* wo = Gout + (size_t)(k8 * 8) * 64 + xc;
        float acc = 0.f;
        uint2 w0 = wo[0], w1 = wo[64], w2 = wo[128], w3 = wo[192];
        uint2 w4 = wo[256], w5 = wo[320], w6 = wo[384], w7 = wo[448];
        acc = dotp(w0.x, pa.x, acc); acc = dotp(w0.y, pa.y, acc);
        acc = dotp(w1.x, pa.z, acc); acc = dotp(w1.y, pa.w, acc);
        acc = dotp(w2.x, pb.x, acc); acc = dotp(w2.y, pb.y, acc);
        acc = dotp(w3.x, pb.z, acc); acc = dotp(w3.y, pb.w, acc);
        acc = dotp(w4.x, pc.x, acc); acc = dotp(w4.y, pc.y, acc);
        acc = dotp(w5.x, pc.z, acc); acc = dotp(w5.y, pc.w, acc);
        acc = dotp(w6.x, pd.x, acc); acc = dotp(w6.y, pd.y, acc);
        acc = dotp(w7.x, pd.z, acc); acc = dotp(w7.y, pd.w, acc);
        pp[k8][xc] = acc;
      }
      __syncthreads();
      // ---- slow phase D: finalize out + transition pt2 for fast path ----
      if (t >= 512 && t < 512 + X_) {
        int xc = t - 512;
        float o = bo;
#pragma unroll
        for (int j = 0; j < 8; ++j) o += pp[j][xc];
        out[(size_t)b * T_ * X_ + (size_t)i * X_ + xc] = o;
        float oo = __shfl_xor(o, 1);
        if (!(t & 1)) xt2[xc >> 1] = pk2(o, oo);
      }
      if (t < H_ && i + 1 >= fs && i + 1 < T_) {
        // skip_p(i+1) tap: h(i+1-2*skip)   [BUGFIX, was i+1-skip]
        float ptn = hn_reg + ring[(i + 1 - 2 * skip) & (RS - 1)][t];
        float po = __shfl_xor(ptn, 1);
        if (!(t & 1)) pt2[t >> 1] = pk2(ptn, po);
      }
      __syncthreads();
    }
  }
}

extern "C" void kernel_launch(void* const* d_in, const int* in_sizes, int n_in,
                              void* d_out, int out_size, void* d_ws,
                              size_t ws_size, hipStream_t stream) {
  (void)in_sizes; (void)n_in; (void)out_size; (void)ws_size;
  // d_in[0] = input [B,T,X] — unused by the reference computation.
  const float* h_enc = (const float*)d_in[1];
  const float* W_ih = (const float*)d_in[2];
  const float* W_hh = (const float*)d_in[3];
  const float* b_ih = (const float*)d_in[4];
  const float* b_hh = (const float*)d_in[5];
  const float* W_out = (const float*)d_in[6];
  const float* b_out = (const float*)d_in[7];
  const int* mask0 = (const int*)d_in[8];
  const int* mask1 = (const int*)d_in[9];
  const int* skipp = (const int*)d_in[10];
  float* out = (float*)d_out;
  uint4* G = (uint4*)d_ws;  // 512 KB fp16 weight images
  const uint2* Gout = (const uint2*)(G + GHH_U4 + GIH_U4);

  int prep_ids = GHH_U4 + GIH_U4 + GOUT_U2 / 2;
  prep_kernel<<<dim3((prep_ids + 255) / 256), dim3(256), 0, stream>>>(
      W_ih, W_hh, W_out, G);
  decoder_kernel<<<dim3(NWG), dim3(NT), 0, stream>>>(
      h_enc, b_ih, b_hh, b_out, mask0, mask1, skipp, G, Gout, out);
}